// Round 8
// baseline (1375.841 us; speedup 1.0000x reference)
//
#include <hip/hip_runtime.h>
#include <stdint.h>

#define NVERT 200000
#define NTET  1000000
#define NE2   3200000          // crossing-edge instance capacity (E[n]=3.0M, sigma~1.2k)
#define NG 1000
#define PAYB 23
#define PAYMASK ((1u<<PAYB)-1u)
#define KB 18
#define KMASK ((1u<<KB)-1u)
#define BSH 13
#define NBIN ((NVERT + (1<<BSH) - 1) >> BSH)   // 25 bins of 8192 a-values

#define SCAN_T 256
#define SCAN_E 16
#define SCAN_EPB (SCAN_T*SCAN_E)   // 4096

__constant__ int c_tri[16][6] = {
  {-1,-1,-1,-1,-1,-1},{1,0,2,-1,-1,-1},{4,0,3,-1,-1,-1},{1,4,2,1,3,4},
  {3,1,5,-1,-1,-1},{2,3,0,2,5,3},{1,4,0,1,5,4},{4,2,5,-1,-1,-1},
  {4,5,2,-1,-1,-1},{4,1,0,4,5,1},{3,2,0,3,5,2},{1,3,5,-1,-1,-1},
  {4,1,2,4,3,1},{3,0,4,-1,-1,-1},{2,0,1,-1,-1,-1},{-1,-1,-1,-1,-1,-1}};
__constant__ int c_ntri[16] = {0,1,1,2,1,2,2,1,1,2,2,1,2,1,1,0};
__constant__ int c_e0[6] = {0,0,0,1,1,2};
__constant__ int c_e1[6] = {1,2,3,2,3,3};

__device__ __forceinline__ uint64_t shfl64(uint64_t x, int src){
  int lo = __shfl((int)(uint32_t)x, src, 64);
  int hi = __shfl((int)(uint32_t)(x >> 32), src, 64);
  return ((uint64_t)(uint32_t)hi << 32) | (uint32_t)lo;
}

// fused: sdf/occ compute + zero bincl/fill/binFill
__global__ void k_init(const float* __restrict__ ssign, const float* __restrict__ sabs,
                       float* __restrict__ sdf, uint8_t* __restrict__ occ,
                       uint32_t* __restrict__ bincl, uint32_t* __restrict__ fill,
                       uint32_t* __restrict__ binFill){
  int i = blockIdx.x*blockDim.x + threadIdx.x;
  if (i >= NVERT) return;
  float s = ssign[i] * fabsf(sabs[i]);
  sdf[i] = s;
  occ[i] = (s > 0.0f) ? 1 : 0;
  bincl[i] = 0u;
  fill[i]  = 0u;
  if (i < NBIN) binFill[i] = 0u;
}

// per-tet: tetindex, packed one|two flags (u64), bucket counts for CROSSING edges
__global__ void k_tet(const int* __restrict__ idx, const uint8_t* __restrict__ occ,
                      uint8_t* __restrict__ tetidx, uint64_t* __restrict__ oneTwo,
                      uint32_t* __restrict__ bcnt){
  int t = blockIdx.x*blockDim.x + threadIdx.x;
  if (t >= NTET) return;
  int4 vv = *(const int4*)&idx[t*4];
  int v[4] = {vv.x, vv.y, vv.z, vv.w};
  int ti = 0;
  #pragma unroll
  for (int j = 0; j < 4; ++j) ti |= (occ[v[j]] ? 1 : 0) << j;
  tetidx[t] = (uint8_t)ti;
  int nt = c_ntri[ti];
  oneTwo[t] = ((nt == 1) ? 1ull : 0ull) | (((nt == 2) ? 1ull : 0ull) << 32);
  if (nt == 0) return;
  #pragma unroll
  for (int e = 0; e < 6; ++e){
    int o0 = (ti >> c_e0[e]) & 1, o1 = (ti >> c_e1[e]) & 1;
    if (o0 == o1) continue;               // only crossing edges enter the pipeline
    int a = v[c_e0[e]], b = v[c_e1[e]];
    if (a > b){ int tmp = a; a = b; b = tmp; }
    atomicAdd((unsigned int*)&bcnt[a], 1u);
  }
}

// ---- in-place inclusive scan, u32 ----
__global__ void k_scan_block(uint32_t* __restrict__ d, uint32_t* __restrict__ part, int L){
  int tid = threadIdx.x;
  int base = blockIdx.x*SCAN_EPB + tid*SCAN_E;
  uint32_t v[SCAN_E];
  #pragma unroll
  for (int j = 0; j < SCAN_E; ++j){
    int i = base + j;
    v[j] = (i < L) ? d[i] : 0u;
  }
  #pragma unroll
  for (int j = 1; j < SCAN_E; ++j) v[j] += v[j-1];
  __shared__ uint32_t s[SCAN_T];
  s[tid] = v[SCAN_E-1];
  __syncthreads();
  for (int o = 1; o < SCAN_T; o <<= 1){
    uint32_t x = (tid >= o) ? s[tid-o] : 0u;
    __syncthreads();
    s[tid] += x;
    __syncthreads();
  }
  uint32_t off = s[tid] - v[SCAN_E-1];
  #pragma unroll
  for (int j = 0; j < SCAN_E; ++j){
    int i = base + j;
    if (i < L) d[i] = v[j] + off;
  }
  if (tid == SCAN_T-1 && part) part[blockIdx.x] = s[SCAN_T-1];
}

__global__ void k_scan_part(uint32_t* __restrict__ part, int n){
  int tid = threadIdx.x;
  int per = (n + SCAN_T - 1)/SCAN_T;
  int st = tid*per, en = st + per; if (en > n) en = n;
  uint32_t sum = 0;
  for (int i = st; i < en; ++i) sum += part[i];
  __shared__ uint32_t s[SCAN_T];
  s[tid] = sum;
  __syncthreads();
  for (int o = 1; o < SCAN_T; o <<= 1){
    uint32_t x = (tid >= o) ? s[tid-o] : 0u;
    __syncthreads();
    s[tid] += x;
    __syncthreads();
  }
  uint32_t off = s[tid] - sum;
  uint32_t run = off;
  for (int i = st; i < en; ++i){ run += part[i]; part[i] = run; }
}

__global__ void k_scan_add(uint32_t* __restrict__ d, const uint32_t* __restrict__ part, int L){
  int blk = blockIdx.x;
  if (blk == 0) return;
  uint32_t off = part[blk-1];
  int base = blk*SCAN_EPB;
  #pragma unroll
  for (int j = 0; j < SCAN_E; ++j){
    int i = base + j*SCAN_T + threadIdx.x;
    if (i < L) d[i] += off;
  }
}

// ---- in-place inclusive scan, u64 (two independent 32-bit fields, no cross-carry) ----
__global__ void k_scan_block64(uint64_t* __restrict__ d, uint64_t* __restrict__ part, int L){
  int tid = threadIdx.x;
  int base = blockIdx.x*SCAN_EPB + tid*SCAN_E;
  uint64_t v[SCAN_E];
  #pragma unroll
  for (int j = 0; j < SCAN_E; ++j){
    int i = base + j;
    v[j] = (i < L) ? d[i] : 0ull;
  }
  #pragma unroll
  for (int j = 1; j < SCAN_E; ++j) v[j] += v[j-1];
  __shared__ uint64_t s[SCAN_T];
  s[tid] = v[SCAN_E-1];
  __syncthreads();
  for (int o = 1; o < SCAN_T; o <<= 1){
    uint64_t x = (tid >= o) ? s[tid-o] : 0ull;
    __syncthreads();
    s[tid] += x;
    __syncthreads();
  }
  uint64_t off = s[tid] - v[SCAN_E-1];
  #pragma unroll
  for (int j = 0; j < SCAN_E; ++j){
    int i = base + j;
    if (i < L) d[i] = v[j] + off;
  }
  if (tid == SCAN_T-1 && part) part[blockIdx.x] = s[SCAN_T-1];
}

__global__ void k_scan_part64(uint64_t* __restrict__ part, int n){
  int tid = threadIdx.x;
  int per = (n + SCAN_T - 1)/SCAN_T;
  int st = tid*per, en = st + per; if (en > n) en = n;
  uint64_t sum = 0;
  for (int i = st; i < en; ++i) sum += part[i];
  __shared__ uint64_t s[SCAN_T];
  s[tid] = sum;
  __syncthreads();
  for (int o = 1; o < SCAN_T; o <<= 1){
    uint64_t x = (tid >= o) ? s[tid-o] : 0ull;
    __syncthreads();
    s[tid] += x;
    __syncthreads();
  }
  uint64_t off = s[tid] - sum;
  uint64_t run = off;
  for (int i = st; i < en; ++i){ run += part[i]; part[i] = run; }
}

__global__ void k_scan_add64(uint64_t* __restrict__ d, const uint64_t* __restrict__ part, int L){
  int blk = blockIdx.x;
  if (blk == 0) return;
  uint64_t off = part[blk-1];
  int base = blk*SCAN_EPB;
  #pragma unroll
  for (int j = 0; j < SCAN_E; ++j){
    int i = base + j*SCAN_T + threadIdx.x;
    if (i < L) d[i] += off;
  }
}

// Pass 1 of the scatter: block-local LDS binning by a>>BSH, then coalesced per-bin
// run flushes into skeyBin. Bin segment bases derive from bincl (bins are
// contiguous a-ranges) -- no extra counters. All per-thread arrays statically indexed.
__global__ void __launch_bounds__(256) k_binscat(const int* __restrict__ idx,
                          const uint8_t* __restrict__ tetidx,
                          const uint32_t* __restrict__ bincl, uint32_t* __restrict__ binFill,
                          uint64_t* __restrict__ skeyBin){
  __shared__ uint32_t hist[NBIN];
  __shared__ uint32_t offs[NBIN];
  __shared__ uint32_t gdest[NBIN];
  __shared__ uint64_t stK[1536];
  __shared__ uint32_t stD[1536];
  int tid = threadIdx.x;
  int t = blockIdx.x*256 + tid;
  if (tid < NBIN) hist[tid] = 0u;
  __syncthreads();
  bool val[6]; uint64_t key[6]; int bin[6]; uint32_t rnk[6];
  int ti = (t < NTET) ? tetidx[t] : 0;
  #pragma unroll
  for (int e = 0; e < 6; ++e){ val[e] = false; key[e] = 0; bin[e] = 0; rnk[e] = 0; }
  if (c_ntri[ti] != 0){
    int4 vv = *(const int4*)&idx[t*4];
    int v[4] = {vv.x, vv.y, vv.z, vv.w};
    #pragma unroll
    for (int e = 0; e < 6; ++e){
      int o0 = (ti >> c_e0[e]) & 1, o1 = (ti >> c_e1[e]) & 1;
      if (o0 == o1) continue;
      int a = v[c_e0[e]], b = v[c_e1[e]];
      if (a > b){ int tmp = a; a = b; b = tmp; }
      val[e] = true;
      key[e] = ((uint64_t)(uint32_t)a << (PAYB+KB)) | ((uint64_t)(uint32_t)b << PAYB)
             | (uint32_t)(t*6 + e);
      bin[e] = a >> BSH;
    }
  }
  #pragma unroll
  for (int e = 0; e < 6; ++e)
    if (val[e]) rnk[e] = atomicAdd(&hist[bin[e]], 1u);
  __syncthreads();
  if (tid == 0){
    uint32_t run = 0;
    for (int b2 = 0; b2 < NBIN; ++b2){ offs[b2] = run; run += hist[b2]; }
  }
  __syncthreads();
  if (tid < NBIN && hist[tid] > 0){
    uint32_t seg = (tid > 0) ? bincl[((uint32_t)tid << BSH) - 1] : 0u;
    gdest[tid] = seg + atomicAdd(&binFill[tid], hist[tid]);
  }
  __syncthreads();
  #pragma unroll
  for (int e = 0; e < 6; ++e){
    if (!val[e]) continue;
    uint32_t o = offs[bin[e]] + rnk[e];
    stK[o] = key[e];
    stD[o] = gdest[bin[e]] + rnk[e];
  }
  __syncthreads();
  uint32_t total = offs[NBIN-1] + hist[NBIN-1];
  for (uint32_t i = tid; i < total; i += 256){
    uint32_t d = stD[i];
    if (d < NE2) skeyBin[d] = stK[i];
  }
}

// Pass 2: one block per bin; scatter within the bin's ~1MB skey segment
// (L2-resident on the block's XCD -> lines accumulate stores before eviction).
__global__ void k_place(const uint64_t* __restrict__ skeyBin, const uint32_t* __restrict__ bincl,
                        uint32_t* __restrict__ fill, uint64_t* __restrict__ skey){
  int b = blockIdx.x;
  uint32_t s = (b > 0) ? bincl[((uint32_t)b << BSH) - 1] : 0u;
  uint32_t hiA = (((uint32_t)b + 1u) << BSH) - 1u; if (hiA > NVERT-1) hiA = NVERT-1;
  uint32_t e = bincl[hiA];
  for (uint32_t i = s + threadIdx.x; i < e; i += blockDim.x){
    uint64_t k = skeyBin[i];
    uint32_t a = (uint32_t)(k >> (PAYB+KB));
    uint32_t base = (a > 0) ? bincl[a-1] : 0u;
    uint32_t p = base + atomicAdd(&fill[a], 1u);
    if (p < NE2) skey[p] = k;
  }
}

// persistent-wave per-bucket rank sort (keys distinct via payload -> strict ranks),
// fused head-flag output into maskA (pre-scan flags).
__global__ void k_bsort(uint64_t* __restrict__ skey, const uint32_t* __restrict__ bincl,
                        uint32_t* __restrict__ maskA){
  int gid  = blockIdx.x*blockDim.x + threadIdx.x;
  int w    = gid >> 6;
  int lane = threadIdx.x & 63;
  int W    = (gridDim.x*blockDim.x) >> 6;
  for (int b = w; b < NVERT; b += W){
    uint32_t s0 = (b > 0) ? bincl[b-1] : 0u;
    uint32_t e0 = bincl[b];
    int n = (int)(e0 - s0);
    if (n <= 0) continue;
    if (n == 1){
      if (lane == 0) maskA[s0] = 1u;
      continue;
    }
    if (n <= 64){
      uint64_t ki = (lane < n) ? skey[s0+lane] : ~0ull;
      int r = 0; bool dup = false;
      for (int j = 0; j < n; ++j){
        uint64_t kj = shfl64(ki, j);
        bool lt = (kj < ki);
        r += lt ? 1 : 0;
        dup |= lt && ((kj >> PAYB) == (ki >> PAYB));
      }
      if (lane < n){
        skey[s0 + r] = ki;
        maskA[s0 + r] = dup ? 0u : 1u;
      }
    } else if (n <= 128){
      int n2 = n - 64;
      uint64_t k0 = skey[s0+lane];                                // first 64 all valid
      uint64_t k1 = (lane < n2) ? skey[s0+64+lane] : ~0ull;
      int r0 = 0, r1 = 0; bool d0 = false, d1 = false;
      for (int j = 0; j < 64; ++j){
        uint64_t kj = shfl64(k0, j);
        bool lt0 = (kj < k0);
        r0 += lt0 ? 1 : 0;  d0 |= lt0 && ((kj >> PAYB) == (k0 >> PAYB));
        bool lt1 = (kj < k1);
        r1 += lt1 ? 1 : 0;  d1 |= lt1 && ((kj >> PAYB) == (k1 >> PAYB));
      }
      for (int j = 0; j < n2; ++j){
        uint64_t kj = shfl64(k1, j);
        bool lt0 = (kj < k0);
        r0 += lt0 ? 1 : 0;  d0 |= lt0 && ((kj >> PAYB) == (k0 >> PAYB));
        bool lt1 = (kj < k1);
        r1 += lt1 ? 1 : 0;  d1 |= lt1 && ((kj >> PAYB) == (k1 >> PAYB));
      }
      { skey[s0 + r0] = k0; maskA[s0 + r0] = d0 ? 0u : 1u; }
      if (lane < n2){ skey[s0 + r1] = k1; maskA[s0 + r1] = d1 ? 0u : 1u; }
    } else if (lane == 0){
      // pathological fallback (never expected at seed 0)
      for (int i = 1; i < n; ++i){
        uint64_t x = skey[s0+i];
        int j = i-1;
        while (j >= 0 && skey[s0+j] > x){ skey[s0+j+1] = skey[s0+j]; --j; }
        skey[s0+j+1] = x;
      }
      maskA[s0] = 1u;
      for (int i = 1; i < n; ++i)
        maskA[s0+i] = ((skey[s0+i] >> PAYB) != (skey[s0+i-1] >> PAYB)) ? 1u : 0u;
    }
  }
}

// per-instance: e2v[payload] = vertex rank (plain store); heads interpolate + write out_verts
__global__ void k_emit(const uint64_t* __restrict__ skey, const uint32_t* __restrict__ maskI,
                       const uint32_t* __restrict__ bincl,
                       const float* __restrict__ verts, const float* __restrict__ deform,
                       const float* __restrict__ sdf,
                       uint32_t* __restrict__ edge2vert, float* __restrict__ out){
  int i = blockIdx.x*blockDim.x + threadIdx.x;
  if (i >= NE2) return;
  uint32_t nE = (uint32_t)__builtin_amdgcn_readfirstlane((int)bincl[NVERT-1]);
  if ((uint32_t)i >= nE) return;
  uint64_t k = skey[i];
  uint32_t m = maskI[i];
  uint32_t pm = (i > 0) ? maskI[i-1] : 0u;
  uint32_t vid = m - 1u;
  edge2vert[(uint32_t)(k & PAYMASK)] = vid;
  if (m == pm) return;                      // duplicate instance
  int a = (int)(k >> (PAYB+KB)), b = (int)((k >> PAYB) & KMASK);
  float sa = sdf[a], sb = sdf[b];
  float denom = sa - sb;
  float w0 = __fdiv_rn(-sb, denom);
  float w1 = __fdiv_rn(sa, denom);
  #pragma unroll
  for (int c = 0; c < 3; ++c){
    float pa = __fadd_rn(verts[a*3+c], __fmul_rn(0.0078125f, deform[a*3+c]));
    float pb = __fadd_rn(verts[b*3+c], __fmul_rn(0.0078125f, deform[b*3+c]));
    out[(size_t)vid*3 + c] = __fadd_rn(__fmul_rn(pa, w0), __fmul_rn(pb, w1));
  }
}

// faces + uv_idx via coalesced edge2vert lookup
__global__ void k_faces(const uint8_t* __restrict__ tetidx,
                        const uint64_t* __restrict__ oneTwoI,
                        const uint32_t* __restrict__ maskI, const uint32_t* __restrict__ bincl,
                        const uint32_t* __restrict__ edge2vert, float* __restrict__ out){
  int t = blockIdx.x*blockDim.x + threadIdx.x;
  if (t >= NTET) return;
  int ti = tetidx[t];
  int nt = c_ntri[ti];
  if (nt == 0) return;
  uint32_t nE      = (uint32_t)__builtin_amdgcn_readfirstlane((int)bincl[NVERT-1]);
  uint32_t nInterp = (uint32_t)__builtin_amdgcn_readfirstlane((int)maskI[nE-1]);
  uint64_t totOT   = oneTwoI[NTET-1];
  uint32_t nOne    = (uint32_t)__builtin_amdgcn_readfirstlane((int)(uint32_t)totOT);
  uint32_t nTwo    = (uint32_t)__builtin_amdgcn_readfirstlane((int)(uint32_t)(totOT >> 32));
  size_t facesOff = (size_t)3*nInterp;
  size_t nFaces = (size_t)nOne + 2u*(size_t)nTwo;
  size_t uvIdxOff = facesOff + 3*nFaces + (size_t)(4*NG*NG)*2;
  uint64_t ot = oneTwoI[t];
  uint32_t oneR = (uint32_t)ot, twoR = (uint32_t)(ot >> 32);
  for (int k = 0; k < nt; ++k){
    size_t row = (nt == 1) ? (size_t)(oneR-1u)
                           : (size_t)nOne + 2u*(size_t)(twoR-1u) + (size_t)k;
    #pragma unroll
    for (int j = 0; j < 3; ++j){
      int e = c_tri[ti][k*3+j];
      out[facesOff + row*3 + j] = (float)edge2vert[t*6 + e];
    }
    int tri = (nt == 2) ? k : 0;
    long long t4 = 4LL*t;
    out[uvIdxOff + row*3 + 0] = (float)t4;
    out[uvIdxOff + row*3 + 1] = (float)(t4 + tri + 1);
    out[uvIdxOff + row*3 + 2] = (float)(t4 + tri + 2);
  }
}

// fixed UV grid (numpy linspace float64 semantics, cast to f32)
__global__ void k_uvs(const uint32_t* __restrict__ maskI, const uint32_t* __restrict__ bincl,
                      const uint64_t* __restrict__ oneTwoI, float* __restrict__ out){
  int r = blockIdx.x*blockDim.x + threadIdx.x;
  if (r >= 4*NG*NG) return;
  uint32_t nE      = (uint32_t)__builtin_amdgcn_readfirstlane((int)bincl[NVERT-1]);
  uint32_t nInterp = (uint32_t)__builtin_amdgcn_readfirstlane((int)maskI[nE-1]);
  uint64_t totOT   = oneTwoI[NTET-1];
  uint32_t nOne    = (uint32_t)__builtin_amdgcn_readfirstlane((int)(uint32_t)totOT);
  uint32_t nTwo    = (uint32_t)__builtin_amdgcn_readfirstlane((int)(uint32_t)(totOT >> 32));
  size_t uvOff = (size_t)3*nInterp + 3*((size_t)nOne + 2u*(size_t)nTwo);
  int cell = r >> 2, c = r & 3;
  int iy = cell / NG, jx = cell % NG;
  const double step = (1.0 - 1.0/NG)/(NG-1);
  float x = (jx == NG-1) ? (float)(1.0 - 1.0/NG) : (float)((double)jx*step);
  float y = (iy == NG-1) ? (float)(1.0 - 1.0/NG) : (float)((double)iy*step);
  float pad = (float)(0.9/NG);
  float u, vv;
  switch (c){
    case 0: u = x;                 vv = y;                 break;
    case 1: u = __fadd_rn(x, pad); vv = y;                 break;
    case 2: u = __fadd_rn(x, pad); vv = __fadd_rn(y, pad); break;
    default:u = x;                 vv = __fadd_rn(y, pad); break;
  }
  out[uvOff + (size_t)r*2 + 0] = u;
  out[uvOff + (size_t)r*2 + 1] = vv;
}

static void scan_u32(uint32_t* d, int L, uint32_t* part, hipStream_t s){
  int nb = (L + SCAN_EPB - 1)/SCAN_EPB;
  k_scan_block<<<nb, SCAN_T, 0, s>>>(d, part, L);
  if (nb > 1){
    k_scan_part<<<1, SCAN_T, 0, s>>>(part, nb);
    k_scan_add<<<nb, SCAN_T, 0, s>>>(d, part, L);
  }
}

static void scan_u64(uint64_t* d, int L, uint64_t* part, hipStream_t s){
  int nb = (L + SCAN_EPB - 1)/SCAN_EPB;
  k_scan_block64<<<nb, SCAN_T, 0, s>>>(d, part, L);
  if (nb > 1){
    k_scan_part64<<<1, SCAN_T, 0, s>>>(part, nb);
    k_scan_add64<<<nb, SCAN_T, 0, s>>>(d, part, L);
  }
}

extern "C" void kernel_launch(void* const* d_in, const int* in_sizes, int n_in,
                              void* d_out, int out_size, void* d_ws, size_t ws_size,
                              hipStream_t stream){
  const float* verts  = (const float*)d_in[0];
  const float* deform = (const float*)d_in[1];
  const float* ssign  = (const float*)d_in[2];
  const float* sabs   = (const float*)d_in[3];
  const int*   idx    = (const int*)d_in[4];
  float* out = (float*)d_out;

  char* ws = (char*)d_ws;
  size_t o = 0;
  auto alloc = [&](size_t bytes) -> void* {
    void* p = ws + o;
    o = (o + bytes + 255) & ~(size_t)255;
    return p;
  };
  float*    sdf     = (float*)   alloc(sizeof(float)*NVERT);
  uint8_t*  occ     = (uint8_t*) alloc(NVERT);
  uint8_t*  tetidx  = (uint8_t*) alloc(NTET);
  uint32_t* bincl   = (uint32_t*)alloc(sizeof(uint32_t)*NVERT);
  uint32_t* fill    = (uint32_t*)alloc(sizeof(uint32_t)*NVERT);
  uint32_t* binFill = (uint32_t*)alloc(sizeof(uint32_t)*64);
  uint64_t* oneTwo  = (uint64_t*)alloc(sizeof(uint64_t)*NTET);
  // union region: skeyBin (NE2 u64) lifetime [binscat, place) overlaps
  // maskI (NE2 u32, live from bsort) + e2v (NTET*6 u32, live from emit)
  size_t unionBytes = sizeof(uint32_t)*NE2 + sizeof(uint32_t)*NTET*6;   // 36.8 MB >= 25.6 MB
  char* unionBase   = (char*)alloc(unionBytes);
  uint64_t* skeyBin = (uint64_t*)unionBase;
  uint32_t* maskI   = (uint32_t*)unionBase;
  uint32_t* e2v     = (uint32_t*)(unionBase + sizeof(uint32_t)*NE2);
  uint64_t* skey    = (uint64_t*)alloc(sizeof(uint64_t)*NE2);
  uint32_t* part    = (uint32_t*)alloc(sizeof(uint32_t)*2048);
  uint64_t* part64  = (uint64_t*)alloc(sizeof(uint64_t)*2048);
  if (o > ws_size) return;  // workspace too small: bail loudly (validation fails)

  k_init<<<(NVERT+255)/256, 256, 0, stream>>>(ssign, sabs, sdf, occ, bincl, fill, binFill);
  k_tet<<<(NTET+255)/256, 256, 0, stream>>>(idx, occ, tetidx, oneTwo, bincl);

  scan_u32(bincl, NVERT, part, stream);

  k_binscat<<<(NTET+255)/256, 256, 0, stream>>>(idx, tetidx, bincl, binFill, skeyBin);
  k_place<<<NBIN, 1024, 0, stream>>>(skeyBin, bincl, fill, skey);
  k_bsort<<<1024, 256, 0, stream>>>(skey, bincl, maskI);

  scan_u32(maskI, NE2, part, stream);
  scan_u64(oneTwo, NTET, part64, stream);

  k_emit<<<(NE2+255)/256, 256, 0, stream>>>(skey, maskI, bincl, verts, deform, sdf, e2v, out);
  k_faces<<<(NTET+255)/256, 256, 0, stream>>>(tetidx, oneTwo, maskI, bincl, e2v, out);
  k_uvs<<<(4*NG*NG+255)/256, 256, 0, stream>>>(maskI, bincl, oneTwo, out);
}

// Round 9
// 718.426 us; speedup vs baseline: 1.9151x; 1.9151x over previous
//
#include <hip/hip_runtime.h>
#include <stdint.h>

#define NVERT 200000
#define NTET  1000000
#define NE2   3200000          // crossing-edge instance capacity (E[n]=3.0M, sigma~1.2k)
#define NG 1000
#define PAYB 23
#define PAYMASK ((1u<<PAYB)-1u)
#define KB 18
#define KMASK ((1u<<KB)-1u)
#define BSH 13
#define NBIN ((NVERT + (1<<BSH) - 1) >> BSH)   // 25 bins of 8192 a-values

#define SCAN_T 256
#define SCAN_E 16
#define SCAN_EPB (SCAN_T*SCAN_E)   // 4096

__constant__ int c_tri[16][6] = {
  {-1,-1,-1,-1,-1,-1},{1,0,2,-1,-1,-1},{4,0,3,-1,-1,-1},{1,4,2,1,3,4},
  {3,1,5,-1,-1,-1},{2,3,0,2,5,3},{1,4,0,1,5,4},{4,2,5,-1,-1,-1},
  {4,5,2,-1,-1,-1},{4,1,0,4,5,1},{3,2,0,3,5,2},{1,3,5,-1,-1,-1},
  {4,1,2,4,3,1},{3,0,4,-1,-1,-1},{2,0,1,-1,-1,-1},{-1,-1,-1,-1,-1,-1}};
__constant__ int c_ntri[16] = {0,1,1,2,1,2,2,1,1,2,2,1,2,1,1,0};
__constant__ int c_e0[6] = {0,0,0,1,1,2};
__constant__ int c_e1[6] = {1,2,3,2,3,3};

__device__ __forceinline__ uint64_t shfl64(uint64_t x, int src){
  int lo = __shfl((int)(uint32_t)x, src, 64);
  int hi = __shfl((int)(uint32_t)(x >> 32), src, 64);
  return ((uint64_t)(uint32_t)hi << 32) | (uint32_t)lo;
}

// fused: sdf/occ compute + zero bincl/fill/binFill
__global__ void k_init(const float* __restrict__ ssign, const float* __restrict__ sabs,
                       float* __restrict__ sdf, uint8_t* __restrict__ occ,
                       uint32_t* __restrict__ bincl, uint32_t* __restrict__ fill,
                       uint32_t* __restrict__ binFill){
  int i = blockIdx.x*blockDim.x + threadIdx.x;
  if (i >= NVERT) return;
  float s = ssign[i] * fabsf(sabs[i]);
  sdf[i] = s;
  occ[i] = (s > 0.0f) ? 1 : 0;
  bincl[i] = 0u;
  fill[i]  = 0u;
  if (i < NBIN) binFill[i] = 0u;
}

// per-tet: tetindex, packed one|two flags (u64), bucket counts for CROSSING edges
__global__ void k_tet(const int* __restrict__ idx, const uint8_t* __restrict__ occ,
                      uint8_t* __restrict__ tetidx, uint64_t* __restrict__ oneTwo,
                      uint32_t* __restrict__ bcnt){
  int t = blockIdx.x*blockDim.x + threadIdx.x;
  if (t >= NTET) return;
  int4 vv = *(const int4*)&idx[t*4];
  int v[4] = {vv.x, vv.y, vv.z, vv.w};
  int ti = 0;
  #pragma unroll
  for (int j = 0; j < 4; ++j) ti |= (occ[v[j]] ? 1 : 0) << j;
  tetidx[t] = (uint8_t)ti;
  int nt = c_ntri[ti];
  oneTwo[t] = ((nt == 1) ? 1ull : 0ull) | (((nt == 2) ? 1ull : 0ull) << 32);
  if (nt == 0) return;
  #pragma unroll
  for (int e = 0; e < 6; ++e){
    int o0 = (ti >> c_e0[e]) & 1, o1 = (ti >> c_e1[e]) & 1;
    if (o0 == o1) continue;               // only crossing edges enter the pipeline
    int a = v[c_e0[e]], b = v[c_e1[e]];
    if (a > b){ int tmp = a; a = b; b = tmp; }
    atomicAdd((unsigned int*)&bcnt[a], 1u);
  }
}

// ---- in-place inclusive scan, u32 ----
__global__ void k_scan_block(uint32_t* __restrict__ d, uint32_t* __restrict__ part, int L){
  int tid = threadIdx.x;
  int base = blockIdx.x*SCAN_EPB + tid*SCAN_E;
  uint32_t v[SCAN_E];
  #pragma unroll
  for (int j = 0; j < SCAN_E; ++j){
    int i = base + j;
    v[j] = (i < L) ? d[i] : 0u;
  }
  #pragma unroll
  for (int j = 1; j < SCAN_E; ++j) v[j] += v[j-1];
  __shared__ uint32_t s[SCAN_T];
  s[tid] = v[SCAN_E-1];
  __syncthreads();
  for (int o = 1; o < SCAN_T; o <<= 1){
    uint32_t x = (tid >= o) ? s[tid-o] : 0u;
    __syncthreads();
    s[tid] += x;
    __syncthreads();
  }
  uint32_t off = s[tid] - v[SCAN_E-1];
  #pragma unroll
  for (int j = 0; j < SCAN_E; ++j){
    int i = base + j;
    if (i < L) d[i] = v[j] + off;
  }
  if (tid == SCAN_T-1 && part) part[blockIdx.x] = s[SCAN_T-1];
}

__global__ void k_scan_part(uint32_t* __restrict__ part, int n){
  int tid = threadIdx.x;
  int per = (n + SCAN_T - 1)/SCAN_T;
  int st = tid*per, en = st + per; if (en > n) en = n;
  uint32_t sum = 0;
  for (int i = st; i < en; ++i) sum += part[i];
  __shared__ uint32_t s[SCAN_T];
  s[tid] = sum;
  __syncthreads();
  for (int o = 1; o < SCAN_T; o <<= 1){
    uint32_t x = (tid >= o) ? s[tid-o] : 0u;
    __syncthreads();
    s[tid] += x;
    __syncthreads();
  }
  uint32_t off = s[tid] - sum;
  uint32_t run = off;
  for (int i = st; i < en; ++i){ run += part[i]; part[i] = run; }
}

__global__ void k_scan_add(uint32_t* __restrict__ d, const uint32_t* __restrict__ part, int L){
  int blk = blockIdx.x;
  if (blk == 0) return;
  uint32_t off = part[blk-1];
  int base = blk*SCAN_EPB;
  #pragma unroll
  for (int j = 0; j < SCAN_E; ++j){
    int i = base + j*SCAN_T + threadIdx.x;
    if (i < L) d[i] += off;
  }
}

// ---- in-place inclusive scan, u64 (two independent 32-bit fields, no cross-carry) ----
__global__ void k_scan_block64(uint64_t* __restrict__ d, uint64_t* __restrict__ part, int L){
  int tid = threadIdx.x;
  int base = blockIdx.x*SCAN_EPB + tid*SCAN_E;
  uint64_t v[SCAN_E];
  #pragma unroll
  for (int j = 0; j < SCAN_E; ++j){
    int i = base + j;
    v[j] = (i < L) ? d[i] : 0ull;
  }
  #pragma unroll
  for (int j = 1; j < SCAN_E; ++j) v[j] += v[j-1];
  __shared__ uint64_t s[SCAN_T];
  s[tid] = v[SCAN_E-1];
  __syncthreads();
  for (int o = 1; o < SCAN_T; o <<= 1){
    uint64_t x = (tid >= o) ? s[tid-o] : 0ull;
    __syncthreads();
    s[tid] += x;
    __syncthreads();
  }
  uint64_t off = s[tid] - v[SCAN_E-1];
  #pragma unroll
  for (int j = 0; j < SCAN_E; ++j){
    int i = base + j;
    if (i < L) d[i] = v[j] + off;
  }
  if (tid == SCAN_T-1 && part) part[blockIdx.x] = s[SCAN_T-1];
}

__global__ void k_scan_part64(uint64_t* __restrict__ part, int n){
  int tid = threadIdx.x;
  int per = (n + SCAN_T - 1)/SCAN_T;
  int st = tid*per, en = st + per; if (en > n) en = n;
  uint64_t sum = 0;
  for (int i = st; i < en; ++i) sum += part[i];
  __shared__ uint64_t s[SCAN_T];
  s[tid] = sum;
  __syncthreads();
  for (int o = 1; o < SCAN_T; o <<= 1){
    uint64_t x = (tid >= o) ? s[tid-o] : 0ull;
    __syncthreads();
    s[tid] += x;
    __syncthreads();
  }
  uint64_t off = s[tid] - sum;
  uint64_t run = off;
  for (int i = st; i < en; ++i){ run += part[i]; part[i] = run; }
}

__global__ void k_scan_add64(uint64_t* __restrict__ d, const uint64_t* __restrict__ part, int L){
  int blk = blockIdx.x;
  if (blk == 0) return;
  uint64_t off = part[blk-1];
  int base = blk*SCAN_EPB;
  #pragma unroll
  for (int j = 0; j < SCAN_E; ++j){
    int i = base + j*SCAN_T + threadIdx.x;
    if (i < L) d[i] += off;
  }
}

// Pass 1 of the scatter: block-local LDS histogram by a>>BSH, then DIRECT per-thread
// writes into the block's reserved per-bin runs in skeyBin (25 contiguous runs/block,
// mostly full lines). No LDS staging of keys.
__global__ void __launch_bounds__(256) k_binscat(const int* __restrict__ idx,
                          const uint8_t* __restrict__ tetidx,
                          const uint32_t* __restrict__ bincl, uint32_t* __restrict__ binFill,
                          uint64_t* __restrict__ skeyBin){
  __shared__ uint32_t hist[NBIN];
  __shared__ uint32_t gdest[NBIN];
  int tid = threadIdx.x;
  int t = blockIdx.x*256 + tid;
  if (tid < NBIN) hist[tid] = 0u;
  __syncthreads();
  bool val[6]; uint64_t key[6]; int bin[6]; uint32_t rnk[6];
  int ti = (t < NTET) ? tetidx[t] : 0;
  #pragma unroll
  for (int e = 0; e < 6; ++e){ val[e] = false; key[e] = 0; bin[e] = 0; rnk[e] = 0; }
  if (c_ntri[ti] != 0){
    int4 vv = *(const int4*)&idx[t*4];
    int v[4] = {vv.x, vv.y, vv.z, vv.w};
    #pragma unroll
    for (int e = 0; e < 6; ++e){
      int o0 = (ti >> c_e0[e]) & 1, o1 = (ti >> c_e1[e]) & 1;
      if (o0 == o1) continue;
      int a = v[c_e0[e]], b = v[c_e1[e]];
      if (a > b){ int tmp = a; a = b; b = tmp; }
      val[e] = true;
      key[e] = ((uint64_t)(uint32_t)a << (PAYB+KB)) | ((uint64_t)(uint32_t)b << PAYB)
             | (uint32_t)(t*6 + e);
      bin[e] = a >> BSH;
    }
  }
  #pragma unroll
  for (int e = 0; e < 6; ++e)
    if (val[e]) rnk[e] = atomicAdd(&hist[bin[e]], 1u);
  __syncthreads();
  if (tid < NBIN && hist[tid] > 0){
    uint32_t seg = (tid > 0) ? bincl[((uint32_t)tid << BSH) - 1] : 0u;
    gdest[tid] = seg + atomicAdd(&binFill[tid], hist[tid]);
  }
  __syncthreads();
  #pragma unroll
  for (int e = 0; e < 6; ++e){
    if (!val[e]) continue;
    uint32_t d = gdest[bin[e]] + rnk[e];
    if (d < NE2) skeyBin[d] = key[e];
  }
}

// Pass 2: grid-strided over all instances; skeyBin is bin-ordered so concurrent
// chunks scatter into the same ~1MB skey window (L2-resident, lines fill before evict).
__global__ void k_place(const uint64_t* __restrict__ skeyBin, const uint32_t* __restrict__ bincl,
                        uint32_t* __restrict__ fill, uint64_t* __restrict__ skey){
  uint32_t nE = (uint32_t)__builtin_amdgcn_readfirstlane((int)bincl[NVERT-1]);
  if (nE > NE2) nE = NE2;
  uint32_t stride = gridDim.x*blockDim.x;
  for (uint32_t i = blockIdx.x*blockDim.x + threadIdx.x; i < nE; i += stride){
    uint64_t k = skeyBin[i];
    uint32_t a = (uint32_t)(k >> (PAYB+KB));
    uint32_t base = (a > 0) ? bincl[a-1] : 0u;
    uint32_t p = base + atomicAdd(&fill[a], 1u);
    if (p < NE2) skey[p] = k;
  }
}

// persistent-wave per-bucket rank sort (keys distinct via payload -> strict ranks),
// fused head-flag output into maskA (pre-scan flags).
__global__ void k_bsort(uint64_t* __restrict__ skey, const uint32_t* __restrict__ bincl,
                        uint32_t* __restrict__ maskA){
  int gid  = blockIdx.x*blockDim.x + threadIdx.x;
  int w    = gid >> 6;
  int lane = threadIdx.x & 63;
  int W    = (gridDim.x*blockDim.x) >> 6;
  for (int b = w; b < NVERT; b += W){
    uint32_t s0 = (b > 0) ? bincl[b-1] : 0u;
    uint32_t e0 = bincl[b];
    int n = (int)(e0 - s0);
    if (n <= 0) continue;
    if (n == 1){
      if (lane == 0) maskA[s0] = 1u;
      continue;
    }
    if (n <= 64){
      uint64_t ki = (lane < n) ? skey[s0+lane] : ~0ull;
      int r = 0; bool dup = false;
      for (int j = 0; j < n; ++j){
        uint64_t kj = shfl64(ki, j);
        bool lt = (kj < ki);
        r += lt ? 1 : 0;
        dup |= lt && ((kj >> PAYB) == (ki >> PAYB));
      }
      if (lane < n){
        skey[s0 + r] = ki;
        maskA[s0 + r] = dup ? 0u : 1u;
      }
    } else if (n <= 128){
      int n2 = n - 64;
      uint64_t k0 = skey[s0+lane];                                // first 64 all valid
      uint64_t k1 = (lane < n2) ? skey[s0+64+lane] : ~0ull;
      int r0 = 0, r1 = 0; bool d0 = false, d1 = false;
      for (int j = 0; j < 64; ++j){
        uint64_t kj = shfl64(k0, j);
        bool lt0 = (kj < k0);
        r0 += lt0 ? 1 : 0;  d0 |= lt0 && ((kj >> PAYB) == (k0 >> PAYB));
        bool lt1 = (kj < k1);
        r1 += lt1 ? 1 : 0;  d1 |= lt1 && ((kj >> PAYB) == (k1 >> PAYB));
      }
      for (int j = 0; j < n2; ++j){
        uint64_t kj = shfl64(k1, j);
        bool lt0 = (kj < k0);
        r0 += lt0 ? 1 : 0;  d0 |= lt0 && ((kj >> PAYB) == (k0 >> PAYB));
        bool lt1 = (kj < k1);
        r1 += lt1 ? 1 : 0;  d1 |= lt1 && ((kj >> PAYB) == (k1 >> PAYB));
      }
      { skey[s0 + r0] = k0; maskA[s0 + r0] = d0 ? 0u : 1u; }
      if (lane < n2){ skey[s0 + r1] = k1; maskA[s0 + r1] = d1 ? 0u : 1u; }
    } else if (lane == 0){
      // pathological fallback (never expected at seed 0)
      for (int i = 1; i < n; ++i){
        uint64_t x = skey[s0+i];
        int j = i-1;
        while (j >= 0 && skey[s0+j] > x){ skey[s0+j+1] = skey[s0+j]; --j; }
        skey[s0+j+1] = x;
      }
      maskA[s0] = 1u;
      for (int i = 1; i < n; ++i)
        maskA[s0+i] = ((skey[s0+i] >> PAYB) != (skey[s0+i-1] >> PAYB)) ? 1u : 0u;
    }
  }
}

// per-instance: e2v[payload] = vertex rank (plain store); heads interpolate + write out_verts
__global__ void k_emit(const uint64_t* __restrict__ skey, const uint32_t* __restrict__ maskI,
                       const uint32_t* __restrict__ bincl,
                       const float* __restrict__ verts, const float* __restrict__ deform,
                       const float* __restrict__ sdf,
                       uint32_t* __restrict__ edge2vert, float* __restrict__ out){
  int i = blockIdx.x*blockDim.x + threadIdx.x;
  if (i >= NE2) return;
  uint32_t nE = (uint32_t)__builtin_amdgcn_readfirstlane((int)bincl[NVERT-1]);
  if ((uint32_t)i >= nE) return;
  uint64_t k = skey[i];
  uint32_t m = maskI[i];
  uint32_t pm = (i > 0) ? maskI[i-1] : 0u;
  uint32_t vid = m - 1u;
  edge2vert[(uint32_t)(k & PAYMASK)] = vid;
  if (m == pm) return;                      // duplicate instance
  int a = (int)(k >> (PAYB+KB)), b = (int)((k >> PAYB) & KMASK);
  float sa = sdf[a], sb = sdf[b];
  float denom = sa - sb;
  float w0 = __fdiv_rn(-sb, denom);
  float w1 = __fdiv_rn(sa, denom);
  #pragma unroll
  for (int c = 0; c < 3; ++c){
    float pa = __fadd_rn(verts[a*3+c], __fmul_rn(0.0078125f, deform[a*3+c]));
    float pb = __fadd_rn(verts[b*3+c], __fmul_rn(0.0078125f, deform[b*3+c]));
    out[(size_t)vid*3 + c] = __fadd_rn(__fmul_rn(pa, w0), __fmul_rn(pb, w1));
  }
}

// faces + uv_idx via coalesced edge2vert lookup
__global__ void k_faces(const uint8_t* __restrict__ tetidx,
                        const uint64_t* __restrict__ oneTwoI,
                        const uint32_t* __restrict__ maskI, const uint32_t* __restrict__ bincl,
                        const uint32_t* __restrict__ edge2vert, float* __restrict__ out){
  int t = blockIdx.x*blockDim.x + threadIdx.x;
  if (t >= NTET) return;
  int ti = tetidx[t];
  int nt = c_ntri[ti];
  if (nt == 0) return;
  uint32_t nE      = (uint32_t)__builtin_amdgcn_readfirstlane((int)bincl[NVERT-1]);
  uint32_t nInterp = (uint32_t)__builtin_amdgcn_readfirstlane((int)maskI[nE-1]);
  uint64_t totOT   = oneTwoI[NTET-1];
  uint32_t nOne    = (uint32_t)__builtin_amdgcn_readfirstlane((int)(uint32_t)totOT);
  uint32_t nTwo    = (uint32_t)__builtin_amdgcn_readfirstlane((int)(uint32_t)(totOT >> 32));
  size_t facesOff = (size_t)3*nInterp;
  size_t nFaces = (size_t)nOne + 2u*(size_t)nTwo;
  size_t uvIdxOff = facesOff + 3*nFaces + (size_t)(4*NG*NG)*2;
  uint64_t ot = oneTwoI[t];
  uint32_t oneR = (uint32_t)ot, twoR = (uint32_t)(ot >> 32);
  for (int k = 0; k < nt; ++k){
    size_t row = (nt == 1) ? (size_t)(oneR-1u)
                           : (size_t)nOne + 2u*(size_t)(twoR-1u) + (size_t)k;
    #pragma unroll
    for (int j = 0; j < 3; ++j){
      int e = c_tri[ti][k*3+j];
      out[facesOff + row*3 + j] = (float)edge2vert[t*6 + e];
    }
    int tri = (nt == 2) ? k : 0;
    long long t4 = 4LL*t;
    out[uvIdxOff + row*3 + 0] = (float)t4;
    out[uvIdxOff + row*3 + 1] = (float)(t4 + tri + 1);
    out[uvIdxOff + row*3 + 2] = (float)(t4 + tri + 2);
  }
}

// fixed UV grid (numpy linspace float64 semantics, cast to f32)
__global__ void k_uvs(const uint32_t* __restrict__ maskI, const uint32_t* __restrict__ bincl,
                      const uint64_t* __restrict__ oneTwoI, float* __restrict__ out){
  int r = blockIdx.x*blockDim.x + threadIdx.x;
  if (r >= 4*NG*NG) return;
  uint32_t nE      = (uint32_t)__builtin_amdgcn_readfirstlane((int)bincl[NVERT-1]);
  uint32_t nInterp = (uint32_t)__builtin_amdgcn_readfirstlane((int)maskI[nE-1]);
  uint64_t totOT   = oneTwoI[NTET-1];
  uint32_t nOne    = (uint32_t)__builtin_amdgcn_readfirstlane((int)(uint32_t)totOT);
  uint32_t nTwo    = (uint32_t)__builtin_amdgcn_readfirstlane((int)(uint32_t)(totOT >> 32));
  size_t uvOff = (size_t)3*nInterp + 3*((size_t)nOne + 2u*(size_t)nTwo);
  int cell = r >> 2, c = r & 3;
  int iy = cell / NG, jx = cell % NG;
  const double step = (1.0 - 1.0/NG)/(NG-1);
  float x = (jx == NG-1) ? (float)(1.0 - 1.0/NG) : (float)((double)jx*step);
  float y = (iy == NG-1) ? (float)(1.0 - 1.0/NG) : (float)((double)iy*step);
  float pad = (float)(0.9/NG);
  float u, vv;
  switch (c){
    case 0: u = x;                 vv = y;                 break;
    case 1: u = __fadd_rn(x, pad); vv = y;                 break;
    case 2: u = __fadd_rn(x, pad); vv = __fadd_rn(y, pad); break;
    default:u = x;                 vv = __fadd_rn(y, pad); break;
  }
  out[uvOff + (size_t)r*2 + 0] = u;
  out[uvOff + (size_t)r*2 + 1] = vv;
}

static void scan_u32(uint32_t* d, int L, uint32_t* part, hipStream_t s){
  int nb = (L + SCAN_EPB - 1)/SCAN_EPB;
  k_scan_block<<<nb, SCAN_T, 0, s>>>(d, part, L);
  if (nb > 1){
    k_scan_part<<<1, SCAN_T, 0, s>>>(part, nb);
    k_scan_add<<<nb, SCAN_T, 0, s>>>(d, part, L);
  }
}

static void scan_u64(uint64_t* d, int L, uint64_t* part, hipStream_t s){
  int nb = (L + SCAN_EPB - 1)/SCAN_EPB;
  k_scan_block64<<<nb, SCAN_T, 0, s>>>(d, part, L);
  if (nb > 1){
    k_scan_part64<<<1, SCAN_T, 0, s>>>(part, nb);
    k_scan_add64<<<nb, SCAN_T, 0, s>>>(d, part, L);
  }
}

extern "C" void kernel_launch(void* const* d_in, const int* in_sizes, int n_in,
                              void* d_out, int out_size, void* d_ws, size_t ws_size,
                              hipStream_t stream){
  const float* verts  = (const float*)d_in[0];
  const float* deform = (const float*)d_in[1];
  const float* ssign  = (const float*)d_in[2];
  const float* sabs   = (const float*)d_in[3];
  const int*   idx    = (const int*)d_in[4];
  float* out = (float*)d_out;

  char* ws = (char*)d_ws;
  size_t o = 0;
  auto alloc = [&](size_t bytes) -> void* {
    void* p = ws + o;
    o = (o + bytes + 255) & ~(size_t)255;
    return p;
  };
  float*    sdf     = (float*)   alloc(sizeof(float)*NVERT);
  uint8_t*  occ     = (uint8_t*) alloc(NVERT);
  uint8_t*  tetidx  = (uint8_t*) alloc(NTET);
  uint32_t* bincl   = (uint32_t*)alloc(sizeof(uint32_t)*NVERT);
  uint32_t* fill    = (uint32_t*)alloc(sizeof(uint32_t)*NVERT);
  uint32_t* binFill = (uint32_t*)alloc(sizeof(uint32_t)*64);
  uint64_t* oneTwo  = (uint64_t*)alloc(sizeof(uint64_t)*NTET);
  // union region: skeyBin (NE2 u64) lifetime [binscat, place) overlaps
  // maskI (NE2 u32, live from bsort) + e2v (NTET*6 u32, live from emit)
  size_t unionBytes = sizeof(uint32_t)*NE2 + sizeof(uint32_t)*NTET*6;   // 36.8 MB >= 25.6 MB
  char* unionBase   = (char*)alloc(unionBytes);
  uint64_t* skeyBin = (uint64_t*)unionBase;
  uint32_t* maskI   = (uint32_t*)unionBase;
  uint32_t* e2v     = (uint32_t*)(unionBase + sizeof(uint32_t)*NE2);
  uint64_t* skey    = (uint64_t*)alloc(sizeof(uint64_t)*NE2);
  uint32_t* part    = (uint32_t*)alloc(sizeof(uint32_t)*2048);
  uint64_t* part64  = (uint64_t*)alloc(sizeof(uint64_t)*2048);
  if (o > ws_size) return;  // workspace too small: bail loudly (validation fails)

  k_init<<<(NVERT+255)/256, 256, 0, stream>>>(ssign, sabs, sdf, occ, bincl, fill, binFill);
  k_tet<<<(NTET+255)/256, 256, 0, stream>>>(idx, occ, tetidx, oneTwo, bincl);

  scan_u32(bincl, NVERT, part, stream);

  k_binscat<<<(NTET+255)/256, 256, 0, stream>>>(idx, tetidx, bincl, binFill, skeyBin);
  k_place<<<2048, 256, 0, stream>>>(skeyBin, bincl, fill, skey);
  k_bsort<<<1024, 256, 0, stream>>>(skey, bincl, maskI);

  scan_u32(maskI, NE2, part, stream);
  scan_u64(oneTwo, NTET, part64, stream);

  k_emit<<<(NE2+255)/256, 256, 0, stream>>>(skey, maskI, bincl, verts, deform, sdf, e2v, out);
  k_faces<<<(NTET+255)/256, 256, 0, stream>>>(tetidx, oneTwo, maskI, bincl, e2v, out);
  k_uvs<<<(4*NG*NG+255)/256, 256, 0, stream>>>(maskI, bincl, oneTwo, out);
}